// Round 11
// baseline (122.496 us; speedup 1.0000x reference)
//
#include <hip/hip_runtime.h>

#define DD 128
#define SS 1024
#define BB 4
#define M_TOT 20000
#define M_PAD 20480   // 64 chunks * 320
#define GM_NCH 64
#define GM_CH 320
#define FMLP_BLOCKS 128
#define PREP_BLOCKS 640   // M_PAD/32

typedef __bf16 bf16x8 __attribute__((ext_vector_type(8)));
typedef _Float16 f16x8 __attribute__((ext_vector_type(8)));
typedef unsigned short u16x8 __attribute__((ext_vector_type(8)));
typedef float f32x16 __attribute__((ext_vector_type(16)));

union BF8 { bf16x8 b; u16x8 u; };

__device__ __forceinline__ unsigned short f2bf(float f) {
    __bf16 h = (__bf16)f;                       // compiler emits HW cvt (RNE)
    return __builtin_bit_cast(unsigned short, h);
}
__device__ __forceinline__ float bf2f(unsigned short h) {
    return __uint_as_float(((unsigned int)h) << 16);
}

// ---------------- k_front: fused {MLP+xnb} (blocks 0..127) and
// {mem prep: mnb bf16, mnT fp16, norm_sq; zero cw,ti} (blocks 128..767, 32 rows each)
__global__ __launch_bounds__(256) void k_front(
    const float* __restrict__ x, const float* __restrict__ W1,
    const float* __restrict__ b1, const float* __restrict__ ln_g,
    const float* __restrict__ ln_b, const float* __restrict__ W2,
    const float* __restrict__ b2, const float* __restrict__ mem,
    unsigned short* __restrict__ xnb, float* __restrict__ raw,
    unsigned short* __restrict__ mnb, _Float16* __restrict__ mnT,
    float* __restrict__ norm_sq, float* __restrict__ ti,
    float* __restrict__ cw) {
    __shared__ __align__(16) char smem_raw[64 * 136 * 2];
    const int tid = threadIdx.x;
    const int bid = blockIdx.x;

    if (bid < FMLP_BLOCKS) {
        // ================= MLP branch =================
        unsigned short* featsL = (unsigned short*)smem_raw;
        float* redp = (float*)(smem_raw + 8704);
        float2* stats = (float2*)(smem_raw + 8704 + 1024);
        const int lane = tid & 63, wv = tid >> 6;
        const int col = lane & 31, hi = lane >> 5;
        const int t0 = bid * 32;
        const int ct = wv;

        bf16x8 Af[8];
        float sq = 0.f;
        const float* xrow = x + (size_t)(t0 + col) * DD + hi * 8;
        #pragma unroll
        for (int kk = 0; kk < 8; ++kk) {
            float4 p = *(const float4*)(xrow + kk * 16);
            float4 q = *(const float4*)(xrow + kk * 16 + 4);
            BF8 t;
            t.u[0] = f2bf(p.x); t.u[1] = f2bf(p.y); t.u[2] = f2bf(p.z); t.u[3] = f2bf(p.w);
            t.u[4] = f2bf(q.x); t.u[5] = f2bf(q.y); t.u[6] = f2bf(q.z); t.u[7] = f2bf(q.w);
            Af[kk] = t.b;
            sq += p.x * p.x + p.y * p.y + p.z * p.z + p.w * p.w;
            sq += q.x * q.x + q.y * q.y + q.z * q.z + q.w * q.w;
        }
        sq += __shfl_xor(sq, 32);
        float xrs = rsqrtf(sq + 1e-12f);
        if (wv == 0) {
            unsigned short* xo = xnb + (size_t)(t0 + col) * DD + hi * 8;
            #pragma unroll
            for (int kk = 0; kk < 8; ++kk) {
                BF8 t; t.b = Af[kk];
                u16x8 o;
                #pragma unroll
                for (int j = 0; j < 8; ++j) o[j] = f2bf(bf2f(t.u[j]) * xrs);
                *(u16x8*)(xo + kk * 16) = o;
            }
        }

        f32x16 acc;
        {
            float bv = b1[ct * 32 + col];
            #pragma unroll
            for (int r = 0; r < 16; ++r) acc[r] = bv;
        }
        const float* w1row = W1 + (size_t)(ct * 32 + col) * DD + hi * 8;
        #pragma unroll
        for (int kk = 0; kk < 8; ++kk) {
            float4 p = *(const float4*)(w1row + kk * 16);
            float4 q = *(const float4*)(w1row + kk * 16 + 4);
            BF8 t;
            t.u[0] = f2bf(p.x); t.u[1] = f2bf(p.y); t.u[2] = f2bf(p.z); t.u[3] = f2bf(p.w);
            t.u[4] = f2bf(q.x); t.u[5] = f2bf(q.y); t.u[6] = f2bf(q.z); t.u[7] = f2bf(q.w);
            acc = __builtin_amdgcn_mfma_f32_32x32x16_bf16(Af[kk], t.b, acc, 0, 0, 0);
        }

        float rs_[16], rq_[16];
        #pragma unroll
        for (int r = 0; r < 16; ++r) { float v = acc[r]; rs_[r] = v; rq_[r] = v * v; }
        #pragma unroll
        for (int off = 1; off < 32; off <<= 1) {
            #pragma unroll
            for (int r = 0; r < 16; ++r) {
                rs_[r] += __shfl_xor(rs_[r], off);
                rq_[r] += __shfl_xor(rq_[r], off);
            }
        }
        if (col == 0) {
            #pragma unroll
            for (int r = 0; r < 16; ++r) {
                int row = (r & 3) + 8 * (r >> 2) + 4 * hi;
                redp[(wv * 32 + row) * 2 + 0] = rs_[r];
                redp[(wv * 32 + row) * 2 + 1] = rq_[r];
            }
        }
        __syncthreads();
        if (tid < 32) {
            float S = redp[(0 * 32 + tid) * 2] + redp[(1 * 32 + tid) * 2] +
                      redp[(2 * 32 + tid) * 2] + redp[(3 * 32 + tid) * 2];
            float Q = redp[(0 * 32 + tid) * 2 + 1] + redp[(1 * 32 + tid) * 2 + 1] +
                      redp[(2 * 32 + tid) * 2 + 1] + redp[(3 * 32 + tid) * 2 + 1];
            float mu = S * (1.f / 128.f);
            float rstd = rsqrtf(Q * (1.f / 128.f) - mu * mu + 1e-5f);
            stats[tid] = make_float2(mu, rstd);
        }
        __syncthreads();

        {
            float gv = ln_g[ct * 32 + col], bv = ln_b[ct * 32 + col];
            #pragma unroll
            for (int r = 0; r < 16; ++r) {
                int row = (r & 3) + 8 * (r >> 2) + 4 * hi;
                float2 st = stats[row];
                float v = fmaxf((acc[r] - st.x) * st.y * gv + bv, 0.f);
                featsL[row * 136 + ct * 32 + col] = f2bf(v);
            }
        }
        __syncthreads();

        f32x16 a2;
        {
            float bv = b2[ct * 32 + col];
            #pragma unroll
            for (int r = 0; r < 16; ++r) a2[r] = bv;
        }
        const float* w2row = W2 + (size_t)(ct * 32 + col) * DD + hi * 8;
        #pragma unroll
        for (int kk = 0; kk < 8; ++kk) {
            bf16x8 Aq = *(const bf16x8*)&featsL[(lane & 31) * 136 + hi * 8 + kk * 16];
            float4 p = *(const float4*)(w2row + kk * 16);
            float4 q = *(const float4*)(w2row + kk * 16 + 4);
            BF8 t;
            t.u[0] = f2bf(p.x); t.u[1] = f2bf(p.y); t.u[2] = f2bf(p.z); t.u[3] = f2bf(p.w);
            t.u[4] = f2bf(q.x); t.u[5] = f2bf(q.y); t.u[6] = f2bf(q.z); t.u[7] = f2bf(q.w);
            a2 = __builtin_amdgcn_mfma_f32_32x32x16_bf16(Aq, t.b, a2, 0, 0, 0);
        }
        #pragma unroll
        for (int r = 0; r < 16; ++r) {
            int row = (r & 3) + 8 * (r >> 2) + 4 * hi;
            raw[(size_t)(t0 + row) * DD + ct * 32 + col] = a2[r];
        }
    } else {
        // ================= prep branch: 32 mem rows per block =================
        unsigned short* RM = (unsigned short*)smem_raw;   // [32][136] u16
        const int pb = bid - FMLP_BLOCKS;                 // 0..639
        const int m0 = pb * 32;
        if (pb < BB * M_PAD / 256) cw[pb * 256 + tid] = 0.0f;
        if (pb == 0 && tid < BB) ti[tid] = 0.0f;

        const int r = tid >> 3, seg = tid & 7;            // 32 rows x 8 segs of 16
        const int m = m0 + r;
        const bool ok = m < M_TOT;
        float4 v[4];
        const float4* src = (const float4*)mem + (size_t)m * 32 + seg * 4;
        #pragma unroll
        for (int i = 0; i < 4; ++i)
            v[i] = ok ? src[i] : make_float4(0.f, 0.f, 0.f, 0.f);
        float ss = 0.f;
        #pragma unroll
        for (int i = 0; i < 4; ++i)
            ss += v[i].x * v[i].x + v[i].y * v[i].y + v[i].z * v[i].z + v[i].w * v[i].w;
        ss += __shfl_xor(ss, 1);
        ss += __shfl_xor(ss, 2);
        ss += __shfl_xor(ss, 4);
        float rs = rsqrtf(ss + 1e-12f);
        if (seg == 0) norm_sq[m] = ss;

        #pragma unroll
        for (int i = 0; i < 2; ++i) {
            float4 a = v[2 * i], bq = v[2 * i + 1];
            u16x8 o;
            o[0] = f2bf(a.x * rs); o[1] = f2bf(a.y * rs);
            o[2] = f2bf(a.z * rs); o[3] = f2bf(a.w * rs);
            o[4] = f2bf(bq.x * rs); o[5] = f2bf(bq.y * rs);
            o[6] = f2bf(bq.z * rs); o[7] = f2bf(bq.w * rs);
            *(u16x8*)(mnb + (size_t)m * DD + seg * 16 + i * 8) = o;
            *(u16x8*)(RM + r * 136 + seg * 16 + i * 8) = o;
        }
        __syncthreads();
        // transposed fp16 write: thread -> (d, half); 16 m per u16x8 pair
        const int d = tid >> 1, half = tid & 1;
        _Float16* dst = mnT + (size_t)d * M_PAD + m0 + half * 16;
        #pragma unroll
        for (int q = 0; q < 2; ++q) {
            f16x8 o;
            #pragma unroll
            for (int j = 0; j < 8; ++j)
                o[j] = (_Float16)bf2f(RM[(half * 16 + q * 8 + j) * 136 + d]);
            *(f16x8*)(dst + q * 8) = o;
        }
    }
}

// ---------------- cw: 4-buffer LDS, ONE barrier per 2 s-tiles, 4 blocks/CU ----------------
__global__ __launch_bounds__(256, 4) void k_cw(
    const unsigned short* __restrict__ xnb, const unsigned short* __restrict__ mnb,
    float* __restrict__ cw) {
    __shared__ unsigned short As[4][32 * 128];
    const int tid = threadIdx.x, lane = tid & 63, wv = tid >> 6;
    const int c = lane & 31, h = lane >> 5;
    const int b = blockIdx.z;
    const int mw = blockIdx.x * 256 + wv * 64;
    const int s_base = blockIdx.y * 256;

    const int srow = tid >> 4, sk16 = tid & 15;
    const int soff = srow * 128 + ((sk16 * 8) ^ ((srow & 15) << 3));
    const int srow1 = srow + 16;
    const int soff1 = srow1 * 128 + ((sk16 * 8) ^ ((srow1 & 15) << 3));
    const unsigned short* xbase = xnb + ((size_t)b * SS + s_base) * DD;

    bf16x8 Bf[2][8];
    #pragma unroll
    for (int ct = 0; ct < 2; ++ct)
        #pragma unroll
        for (int kk = 0; kk < 8; ++kk)
            Bf[ct][kk] = *(const bf16x8*)(mnb + (size_t)(mw + ct * 32 + c) * DD +
                                          kk * 16 + h * 8);

    {
        u16x8 a0 = *(const u16x8*)(xbase + (size_t)srow * DD + sk16 * 8);
        u16x8 a1 = *(const u16x8*)(xbase + (size_t)srow1 * DD + sk16 * 8);
        const unsigned short* n1 = xbase + (size_t)32 * DD;
        u16x8 b0 = *(const u16x8*)(n1 + (size_t)srow * DD + sk16 * 8);
        u16x8 b1 = *(const u16x8*)(n1 + (size_t)srow1 * DD + sk16 * 8);
        *(u16x8*)&As[0][soff] = a0; *(u16x8*)&As[0][soff1] = a1;
        *(u16x8*)&As[1][soff] = b0; *(u16x8*)&As[1][soff1] = b1;
    }

    float cw0 = 0.f, cw1 = 0.f;
    #pragma unroll 1
    for (int p = 0; p < 4; ++p) {
        __syncthreads();
        u16x8 w0, w1;
        if (p < 3) {   // first prefetch pair (keeps live staging regs low)
            const unsigned short* n0 = xbase + (size_t)(2 * p + 2) * 32 * DD;
            w0 = *(const u16x8*)(n0 + (size_t)srow * DD + sk16 * 8);
            w1 = *(const u16x8*)(n0 + (size_t)srow1 * DD + sk16 * 8);
        }
        {
            f32x16 p0, p1;
            #pragma unroll
            for (int r = 0; r < 16; ++r) { p0[r] = 0.f; p1[r] = 0.f; }
            const unsigned short* Ab = As[(2 * p) & 3];
            __builtin_amdgcn_s_setprio(1);
            #pragma unroll
            for (int kk = 0; kk < 8; ++kk) {
                bf16x8 Afr = *(const bf16x8*)&Ab[c * 128 + ((kk * 16 + h * 8) ^ ((c & 15) << 3))];
                p0 = __builtin_amdgcn_mfma_f32_32x32x16_bf16(Afr, Bf[0][kk], p0, 0, 0, 0);
                p1 = __builtin_amdgcn_mfma_f32_32x32x16_bf16(Afr, Bf[1][kk], p1, 0, 0, 0);
            }
            __builtin_amdgcn_s_setprio(0);
            #pragma unroll
            for (int r = 0; r < 16; ++r) {
                float a = p0[r], bb = p1[r];
                cw0 += a > 0.1f ? a : 0.f;
                cw1 += bb > 0.1f ? bb : 0.f;
            }
        }
        u16x8 w2, w3;
        if (p < 3) {   // second prefetch pair
            const unsigned short* n1 = xbase + (size_t)(2 * p + 3) * 32 * DD;
            w2 = *(const u16x8*)(n1 + (size_t)srow * DD + sk16 * 8);
            w3 = *(const u16x8*)(n1 + (size_t)srow1 * DD + sk16 * 8);
        }
        {
            f32x16 p0, p1;
            #pragma unroll
            for (int r = 0; r < 16; ++r) { p0[r] = 0.f; p1[r] = 0.f; }
            const unsigned short* Ab = As[(2 * p + 1) & 3];
            __builtin_amdgcn_s_setprio(1);
            #pragma unroll
            for (int kk = 0; kk < 8; ++kk) {
                bf16x8 Afr = *(const bf16x8*)&Ab[c * 128 + ((kk * 16 + h * 8) ^ ((c & 15) << 3))];
                p0 = __builtin_amdgcn_mfma_f32_32x32x16_bf16(Afr, Bf[0][kk], p0, 0, 0, 0);
                p1 = __builtin_amdgcn_mfma_f32_32x32x16_bf16(Afr, Bf[1][kk], p1, 0, 0, 0);
            }
            __builtin_amdgcn_s_setprio(0);
            if (p < 3) {
                unsigned short* An0 = As[(2 * p + 2) & 3];
                unsigned short* An1 = As[(2 * p + 3) & 3];
                *(u16x8*)&An0[soff] = w0; *(u16x8*)&An0[soff1] = w1;
                *(u16x8*)&An1[soff] = w2; *(u16x8*)&An1[soff1] = w3;
            }
            #pragma unroll
            for (int r = 0; r < 16; ++r) {
                float a = p0[r], bb = p1[r];
                cw0 += a > 0.1f ? a : 0.f;
                cw1 += bb > 0.1f ? bb : 0.f;
            }
        }
    }
    cw0 += __shfl_xor(cw0, 32);
    cw1 += __shfl_xor(cw1, 32);
    if (lane < 32) {
        atomicAdd(&cw[(size_t)b * M_PAD + mw + c], cw0);
        atomicAdd(&cw[(size_t)b * M_PAD + mw + 32 + c], cw1);
    }
}

// ---------------- gmat: fp16 MFMA full-G per block -> fp16 pG partials ----------------
__global__ __launch_bounds__(256) void k_gmatm(
    const _Float16* __restrict__ mnT, const float* __restrict__ cw,
    const float* __restrict__ norm_sq, float* __restrict__ ti,
    _Float16* __restrict__ pG) {
    __shared__ __align__(16) _Float16 effH[GM_CH];
    __shared__ float rb[4];
    const int tid = threadIdx.x, lane = tid & 63, wv = tid >> 6;
    const int c = lane & 31, h = lane >> 5;
    const int b = blockIdx.y;
    const int m0 = blockIdx.x * GM_CH;

    float tsum = 0.f;
    #pragma unroll
    for (int idx = tid; idx < GM_CH; idx += 256) {
        int m = m0 + idx;
        float e = 0.f;
        if (m < M_TOT) {
            float cc = cw[(size_t)b * M_PAD + m];
            float ns = norm_sq[m];
            e = (cc > 0.01f && ns > 1e-6f) ? cc : 0.f;
        }
        effH[idx] = (_Float16)e;
        tsum += e;
    }
    #pragma unroll
    for (int off = 1; off < 64; off <<= 1) tsum += __shfl_xor(tsum, off);
    if (lane == 0) rb[wv] = tsum;
    __syncthreads();
    if (tid == 0) atomicAdd(&ti[b], rb[0] + rb[1] + rb[2] + rb[3]);

    f32x16 a0, a1, a2, a3;
    #pragma unroll
    for (int r = 0; r < 16; ++r) { a0[r] = 0.f; a1[r] = 0.f; a2[r] = 0.f; a3[r] = 0.f; }

    const _Float16* Arow = mnT + (size_t)(wv * 32 + c) * M_PAD + m0;
    const _Float16* B0r = mnT + (size_t)(0 * 32 + c) * M_PAD + m0;
    const _Float16* B1r = mnT + (size_t)(1 * 32 + c) * M_PAD + m0;
    const _Float16* B2r = mnT + (size_t)(2 * 32 + c) * M_PAD + m0;
    const _Float16* B3r = mnT + (size_t)(3 * 32 + c) * M_PAD + m0;

    #pragma unroll 1
    for (int t = 0; t < GM_CH / 64; ++t) {
        #pragma unroll
        for (int kk = 0; kk < 4; ++kk) {
            const int mo = t * 64 + kk * 16 + h * 8;
            f16x8 au = *(const f16x8*)(Arow + mo);
            f16x8 ef = *(const f16x8*)&effH[mo];
            f16x8 af = au * ef;                      // v_pk_mul_f16 x4
            f16x8 B0 = *(const f16x8*)(B0r + mo);
            f16x8 B1 = *(const f16x8*)(B1r + mo);
            f16x8 B2 = *(const f16x8*)(B2r + mo);
            f16x8 B3 = *(const f16x8*)(B3r + mo);
            a0 = __builtin_amdgcn_mfma_f32_32x32x16_f16(af, B0, a0, 0, 0, 0);
            a1 = __builtin_amdgcn_mfma_f32_32x32x16_f16(af, B1, a1, 0, 0, 0);
            a2 = __builtin_amdgcn_mfma_f32_32x32x16_f16(af, B2, a2, 0, 0, 0);
            a3 = __builtin_amdgcn_mfma_f32_32x32x16_f16(af, B3, a3, 0, 0, 0);
        }
    }
    _Float16* o = pG + (size_t)(blockIdx.x * BB + b) * (DD * DD);
    #pragma unroll
    for (int r = 0; r < 16; ++r) {
        int rf = (r & 3) + 8 * (r >> 2) + 4 * h;
        o[(wv * 32 + rf) * DD + 0 * 32 + c] = (_Float16)a0[r];
        o[(wv * 32 + rf) * DD + 1 * 32 + c] = (_Float16)a1[r];
        o[(wv * 32 + rf) * DD + 2 * 32 + c] = (_Float16)a2[r];
        o[(wv * 32 + rf) * DD + 3 * 32 + c] = (_Float16)a3[r];
    }
}

// ---------------- gmat stage 2: reduce fp16 partials -> bf16 G ----------------
__global__ __launch_bounds__(256) void k_gmat2(const _Float16* __restrict__ pG,
                                               unsigned short* __restrict__ Gb) {
    __shared__ float red[4][64][8];
    const int tid = threadIdx.x;
    const int b = blockIdx.y;
    const int sl = tid & 63, cg = tid >> 6;
    const int f8i = blockIdx.x * 64 + sl;
    float acc[8] = {0.f, 0.f, 0.f, 0.f, 0.f, 0.f, 0.f, 0.f};
    for (int c = cg; c < GM_NCH; c += 4) {
        f16x8 p = *(const f16x8*)(pG + (size_t)(c * BB + b) * (DD * DD) + (size_t)f8i * 8);
        #pragma unroll
        for (int j = 0; j < 8; ++j) acc[j] += (float)p[j];
    }
    #pragma unroll
    for (int j = 0; j < 8; ++j) red[cg][sl][j] = acc[j];
    __syncthreads();
    if (tid < 64) {
        u16x8 o;
        #pragma unroll
        for (int j = 0; j < 8; ++j)
            o[j] = f2bf(red[0][tid][j] + red[1][tid][j] + red[2][tid][j] + red[3][tid][j]);
        *(u16x8*)&Gb[(size_t)b * DD * DD + (size_t)(blockIdx.x * 64 + tid) * 8] = o;
    }
}

// ---------------- final = raw + scale * (raw @ G_b), col-split: 256 blocks ----------------
__global__ __launch_bounds__(128) void k_final(
    const float* __restrict__ raw, const unsigned short* __restrict__ Gb,
    const float* __restrict__ ti, float* __restrict__ out) {
    const int tid = threadIdx.x, lane = tid & 63, wv = tid >> 6;   // wv 0..1
    const int col = lane & 31, hi = lane >> 5;
    const int t0 = blockIdx.x * 32;
    const int b = blockIdx.x >> 5;
    const int ct = blockIdx.y * 2 + wv;   // col tile 0..3

    bf16x8 Af[8];
    const float* rrow = raw + (size_t)(t0 + col) * DD + hi * 8;
    #pragma unroll
    for (int kk = 0; kk < 8; ++kk) {
        float4 p = *(const float4*)(rrow + kk * 16);
        float4 q = *(const float4*)(rrow + kk * 16 + 4);
        BF8 t;
        t.u[0] = f2bf(p.x); t.u[1] = f2bf(p.y); t.u[2] = f2bf(p.z); t.u[3] = f2bf(p.w);
        t.u[4] = f2bf(q.x); t.u[5] = f2bf(q.y); t.u[6] = f2bf(q.z); t.u[7] = f2bf(q.w);
        Af[kk] = t.b;
    }
    f32x16 acc;
    #pragma unroll
    for (int r = 0; r < 16; ++r) acc[r] = 0.f;
    const unsigned short* grow = Gb + (size_t)b * DD * DD + (size_t)(ct * 32 + col) * DD + hi * 8;
    #pragma unroll
    for (int kk = 0; kk < 8; ++kk) {
        bf16x8 Bw = *(const bf16x8*)(grow + kk * 16);
        acc = __builtin_amdgcn_mfma_f32_32x32x16_bf16(Af[kk], Bw, acc, 0, 0, 0);
    }
    float tib = ti[b];
    float scale = (tib > 0.01f) ? 0.5f / (tib + 1e-5f) : 0.0f;
    #pragma unroll
    for (int r = 0; r < 16; ++r) {
        int row = (r & 3) + 8 * (r >> 2) + 4 * hi;
        size_t idx = (size_t)(t0 + row) * DD + ct * 32 + col;
        out[idx] = raw[idx] + scale * acc[r];
    }
}

extern "C" void kernel_launch(void* const* d_in, const int* in_sizes, int n_in,
                              void* d_out, int out_size, void* d_ws, size_t ws_size,
                              hipStream_t stream) {
    const float* x   = (const float*)d_in[0];
    const float* mem = (const float*)d_in[1];
    const float* W1  = (const float*)d_in[2];
    const float* b1  = (const float*)d_in[3];
    const float* lg  = (const float*)d_in[4];
    const float* lb  = (const float*)d_in[5];
    const float* W2  = (const float*)d_in[6];
    const float* b2  = (const float*)d_in[7];
    float* out = (float*)d_out;

    float* wsf = (float*)d_ws;
    size_t off = 0;
    unsigned short* mnb = (unsigned short*)(wsf + off); off += (size_t)M_PAD * 64;
    _Float16* mnT = (_Float16*)(wsf + off);             off += (size_t)M_PAD * 64;
    float* norm_sq = wsf + off;                         off += M_PAD;
    unsigned short* xnb = (unsigned short*)(wsf + off); off += (size_t)BB * SS * 64;
    float* raw = wsf + off;                             off += (size_t)BB * SS * DD;
    float* cw  = wsf + off;                             off += (size_t)BB * M_PAD;
    unsigned short* Gb = (unsigned short*)(wsf + off);  off += (size_t)BB * DD * DD / 2;
    float* ti  = wsf + off;                             off += BB;
    _Float16* pG = (_Float16*)(wsf + off);              off += (size_t)GM_NCH * BB * DD * DD / 2;

    k_front<<<dim3(FMLP_BLOCKS + PREP_BLOCKS), 256, 0, stream>>>(
        x, W1, b1, lg, lb, W2, b2, mem, xnb, raw, mnb, mnT, norm_sq, ti, cw);
    k_cw<<<dim3(M_PAD / 256, 4, BB), 256, 0, stream>>>(xnb, mnb, cw);
    k_gmatm<<<dim3(GM_NCH, BB), 256, 0, stream>>>(mnT, cw, norm_sq, ti, pG);
    k_gmat2<<<dim3(DD * DD / 512, BB), 256, 0, stream>>>(pG, Gb);
    k_final<<<dim3(SS * BB / 32, 2), 128, 0, stream>>>(raw, Gb, ti, out);
}

// Round 12
// 74.317 us; speedup vs baseline: 1.6483x; 1.6483x over previous
//
#include <hip/hip_runtime.h>

#define DD 128
#define SS 1024
#define BB 4
#define M_TOT 20000
#define M_PAD 20480   // 64 chunks * 320
#define GM_NCH 64
#define GM_CH 320
#define FMLP_BLOCKS 128
#define PREP_BLOCKS 640   // M_PAD/32

typedef __bf16 bf16x8 __attribute__((ext_vector_type(8)));
typedef _Float16 f16x8 __attribute__((ext_vector_type(8)));
typedef unsigned short u16x8 __attribute__((ext_vector_type(8)));
typedef float f32x16 __attribute__((ext_vector_type(16)));

union BF8 { bf16x8 b; u16x8 u; };

__device__ __forceinline__ unsigned short f2bf(float f) {
    __bf16 h = (__bf16)f;                       // compiler emits HW cvt (RNE)
    return __builtin_bit_cast(unsigned short, h);
}
__device__ __forceinline__ float bf2f(unsigned short h) {
    return __uint_as_float(((unsigned int)h) << 16);
}

// ---------------- k_front: fused {MLP+xnb} (blocks 0..127) and
// {mem prep: mnb bf16, mnT fp16, norm_sq; zero cw,ti} (blocks 128..767, 32 rows each)
__global__ __launch_bounds__(256) void k_front(
    const float* __restrict__ x, const float* __restrict__ W1,
    const float* __restrict__ b1, const float* __restrict__ ln_g,
    const float* __restrict__ ln_b, const float* __restrict__ W2,
    const float* __restrict__ b2, const float* __restrict__ mem,
    unsigned short* __restrict__ xnb, float* __restrict__ raw,
    unsigned short* __restrict__ mnb, _Float16* __restrict__ mnT,
    float* __restrict__ norm_sq, float* __restrict__ ti,
    float* __restrict__ cw) {
    __shared__ __align__(16) char smem_raw[64 * 136 * 2];
    const int tid = threadIdx.x;
    const int bid = blockIdx.x;

    if (bid < FMLP_BLOCKS) {
        // ================= MLP branch =================
        unsigned short* featsL = (unsigned short*)smem_raw;
        float* redp = (float*)(smem_raw + 8704);
        float2* stats = (float2*)(smem_raw + 8704 + 1024);
        const int lane = tid & 63, wv = tid >> 6;
        const int col = lane & 31, hi = lane >> 5;
        const int t0 = bid * 32;
        const int ct = wv;

        bf16x8 Af[8];
        float sq = 0.f;
        const float* xrow = x + (size_t)(t0 + col) * DD + hi * 8;
        #pragma unroll
        for (int kk = 0; kk < 8; ++kk) {
            float4 p = *(const float4*)(xrow + kk * 16);
            float4 q = *(const float4*)(xrow + kk * 16 + 4);
            BF8 t;
            t.u[0] = f2bf(p.x); t.u[1] = f2bf(p.y); t.u[2] = f2bf(p.z); t.u[3] = f2bf(p.w);
            t.u[4] = f2bf(q.x); t.u[5] = f2bf(q.y); t.u[6] = f2bf(q.z); t.u[7] = f2bf(q.w);
            Af[kk] = t.b;
            sq += p.x * p.x + p.y * p.y + p.z * p.z + p.w * p.w;
            sq += q.x * q.x + q.y * q.y + q.z * q.z + q.w * q.w;
        }
        sq += __shfl_xor(sq, 32);
        float xrs = rsqrtf(sq + 1e-12f);
        if (wv == 0) {
            unsigned short* xo = xnb + (size_t)(t0 + col) * DD + hi * 8;
            #pragma unroll
            for (int kk = 0; kk < 8; ++kk) {
                BF8 t; t.b = Af[kk];
                u16x8 o;
                #pragma unroll
                for (int j = 0; j < 8; ++j) o[j] = f2bf(bf2f(t.u[j]) * xrs);
                *(u16x8*)(xo + kk * 16) = o;
            }
        }

        f32x16 acc;
        {
            float bv = b1[ct * 32 + col];
            #pragma unroll
            for (int r = 0; r < 16; ++r) acc[r] = bv;
        }
        const float* w1row = W1 + (size_t)(ct * 32 + col) * DD + hi * 8;
        #pragma unroll
        for (int kk = 0; kk < 8; ++kk) {
            float4 p = *(const float4*)(w1row + kk * 16);
            float4 q = *(const float4*)(w1row + kk * 16 + 4);
            BF8 t;
            t.u[0] = f2bf(p.x); t.u[1] = f2bf(p.y); t.u[2] = f2bf(p.z); t.u[3] = f2bf(p.w);
            t.u[4] = f2bf(q.x); t.u[5] = f2bf(q.y); t.u[6] = f2bf(q.z); t.u[7] = f2bf(q.w);
            acc = __builtin_amdgcn_mfma_f32_32x32x16_bf16(Af[kk], t.b, acc, 0, 0, 0);
        }

        float rs_[16], rq_[16];
        #pragma unroll
        for (int r = 0; r < 16; ++r) { float v = acc[r]; rs_[r] = v; rq_[r] = v * v; }
        #pragma unroll
        for (int off = 1; off < 32; off <<= 1) {
            #pragma unroll
            for (int r = 0; r < 16; ++r) {
                rs_[r] += __shfl_xor(rs_[r], off);
                rq_[r] += __shfl_xor(rq_[r], off);
            }
        }
        if (col == 0) {
            #pragma unroll
            for (int r = 0; r < 16; ++r) {
                int row = (r & 3) + 8 * (r >> 2) + 4 * hi;
                redp[(wv * 32 + row) * 2 + 0] = rs_[r];
                redp[(wv * 32 + row) * 2 + 1] = rq_[r];
            }
        }
        __syncthreads();
        if (tid < 32) {
            float S = redp[(0 * 32 + tid) * 2] + redp[(1 * 32 + tid) * 2] +
                      redp[(2 * 32 + tid) * 2] + redp[(3 * 32 + tid) * 2];
            float Q = redp[(0 * 32 + tid) * 2 + 1] + redp[(1 * 32 + tid) * 2 + 1] +
                      redp[(2 * 32 + tid) * 2 + 1] + redp[(3 * 32 + tid) * 2 + 1];
            float mu = S * (1.f / 128.f);
            float rstd = rsqrtf(Q * (1.f / 128.f) - mu * mu + 1e-5f);
            stats[tid] = make_float2(mu, rstd);
        }
        __syncthreads();

        {
            float gv = ln_g[ct * 32 + col], bv = ln_b[ct * 32 + col];
            #pragma unroll
            for (int r = 0; r < 16; ++r) {
                int row = (r & 3) + 8 * (r >> 2) + 4 * hi;
                float2 st = stats[row];
                float v = fmaxf((acc[r] - st.x) * st.y * gv + bv, 0.f);
                featsL[row * 136 + ct * 32 + col] = f2bf(v);
            }
        }
        __syncthreads();

        f32x16 a2;
        {
            float bv = b2[ct * 32 + col];
            #pragma unroll
            for (int r = 0; r < 16; ++r) a2[r] = bv;
        }
        const float* w2row = W2 + (size_t)(ct * 32 + col) * DD + hi * 8;
        #pragma unroll
        for (int kk = 0; kk < 8; ++kk) {
            bf16x8 Aq = *(const bf16x8*)&featsL[(lane & 31) * 136 + hi * 8 + kk * 16];
            float4 p = *(const float4*)(w2row + kk * 16);
            float4 q = *(const float4*)(w2row + kk * 16 + 4);
            BF8 t;
            t.u[0] = f2bf(p.x); t.u[1] = f2bf(p.y); t.u[2] = f2bf(p.z); t.u[3] = f2bf(p.w);
            t.u[4] = f2bf(q.x); t.u[5] = f2bf(q.y); t.u[6] = f2bf(q.z); t.u[7] = f2bf(q.w);
            a2 = __builtin_amdgcn_mfma_f32_32x32x16_bf16(Aq, t.b, a2, 0, 0, 0);
        }
        #pragma unroll
        for (int r = 0; r < 16; ++r) {
            int row = (r & 3) + 8 * (r >> 2) + 4 * hi;
            raw[(size_t)(t0 + row) * DD + ct * 32 + col] = a2[r];
        }
    } else {
        // ================= prep branch: 32 mem rows per block =================
        unsigned short* RM = (unsigned short*)smem_raw;   // [32][136] u16
        const int pb = bid - FMLP_BLOCKS;                 // 0..639
        const int m0 = pb * 32;
        if (pb < BB * M_PAD / 256) cw[pb * 256 + tid] = 0.0f;
        if (pb == 0 && tid < BB) ti[tid] = 0.0f;

        const int r = tid >> 3, seg = tid & 7;            // 32 rows x 8 segs of 16
        const int m = m0 + r;
        const bool ok = m < M_TOT;
        float4 v[4];
        const float4* src = (const float4*)mem + (size_t)m * 32 + seg * 4;
        #pragma unroll
        for (int i = 0; i < 4; ++i)
            v[i] = ok ? src[i] : make_float4(0.f, 0.f, 0.f, 0.f);
        float ss = 0.f;
        #pragma unroll
        for (int i = 0; i < 4; ++i)
            ss += v[i].x * v[i].x + v[i].y * v[i].y + v[i].z * v[i].z + v[i].w * v[i].w;
        ss += __shfl_xor(ss, 1);
        ss += __shfl_xor(ss, 2);
        ss += __shfl_xor(ss, 4);
        float rs = rsqrtf(ss + 1e-12f);
        if (seg == 0) norm_sq[m] = ss;

        #pragma unroll
        for (int i = 0; i < 2; ++i) {
            float4 a = v[2 * i], bq = v[2 * i + 1];
            u16x8 o;
            o[0] = f2bf(a.x * rs); o[1] = f2bf(a.y * rs);
            o[2] = f2bf(a.z * rs); o[3] = f2bf(a.w * rs);
            o[4] = f2bf(bq.x * rs); o[5] = f2bf(bq.y * rs);
            o[6] = f2bf(bq.z * rs); o[7] = f2bf(bq.w * rs);
            *(u16x8*)(mnb + (size_t)m * DD + seg * 16 + i * 8) = o;
            *(u16x8*)(RM + r * 136 + seg * 16 + i * 8) = o;
        }
        __syncthreads();
        // transposed fp16 write: thread -> (d, half); 16 m per u16x8 pair
        const int d = tid >> 1, half = tid & 1;
        _Float16* dst = mnT + (size_t)d * M_PAD + m0 + half * 16;
        #pragma unroll
        for (int q = 0; q < 2; ++q) {
            f16x8 o;
            #pragma unroll
            for (int j = 0; j < 8; ++j)
                o[j] = (_Float16)bf2f(RM[(half * 16 + q * 8 + j) * 136 + d]);
            *(f16x8*)(dst + q * 8) = o;
        }
    }
}

// ---------------- cw: 4-buffer LDS, ONE barrier per 2 s-tiles (round-10 proven) ----------------
__global__ __launch_bounds__(256, 3) void k_cw(
    const unsigned short* __restrict__ xnb, const unsigned short* __restrict__ mnb,
    float* __restrict__ cw) {
    __shared__ unsigned short As[4][32 * 128];
    const int tid = threadIdx.x, lane = tid & 63, wv = tid >> 6;
    const int c = lane & 31, h = lane >> 5;
    const int b = blockIdx.z;
    const int mw = blockIdx.x * 256 + wv * 64;
    const int s_base = blockIdx.y * 256;

    const int srow = tid >> 4, sk16 = tid & 15;
    const int soff = srow * 128 + ((sk16 * 8) ^ ((srow & 15) << 3));
    const int srow1 = srow + 16;
    const int soff1 = srow1 * 128 + ((sk16 * 8) ^ ((srow1 & 15) << 3));
    const unsigned short* xbase = xnb + ((size_t)b * SS + s_base) * DD;

    bf16x8 Bf[2][8];
    #pragma unroll
    for (int ct = 0; ct < 2; ++ct)
        #pragma unroll
        for (int kk = 0; kk < 8; ++kk)
            Bf[ct][kk] = *(const bf16x8*)(mnb + (size_t)(mw + ct * 32 + c) * DD +
                                          kk * 16 + h * 8);

    {
        u16x8 a0 = *(const u16x8*)(xbase + (size_t)srow * DD + sk16 * 8);
        u16x8 a1 = *(const u16x8*)(xbase + (size_t)srow1 * DD + sk16 * 8);
        const unsigned short* n1 = xbase + (size_t)32 * DD;
        u16x8 b0 = *(const u16x8*)(n1 + (size_t)srow * DD + sk16 * 8);
        u16x8 b1 = *(const u16x8*)(n1 + (size_t)srow1 * DD + sk16 * 8);
        *(u16x8*)&As[0][soff] = a0; *(u16x8*)&As[0][soff1] = a1;
        *(u16x8*)&As[1][soff] = b0; *(u16x8*)&As[1][soff1] = b1;
    }

    float cw0 = 0.f, cw1 = 0.f;
    #pragma unroll 1
    for (int p = 0; p < 4; ++p) {
        __syncthreads();
        u16x8 w0, w1, w2, w3;
        if (p < 3) {
            const unsigned short* n0 = xbase + (size_t)(2 * p + 2) * 32 * DD;
            const unsigned short* n1 = xbase + (size_t)(2 * p + 3) * 32 * DD;
            w0 = *(const u16x8*)(n0 + (size_t)srow * DD + sk16 * 8);
            w1 = *(const u16x8*)(n0 + (size_t)srow1 * DD + sk16 * 8);
            w2 = *(const u16x8*)(n1 + (size_t)srow * DD + sk16 * 8);
            w3 = *(const u16x8*)(n1 + (size_t)srow1 * DD + sk16 * 8);
        }
        {
            f32x16 p0, p1;
            #pragma unroll
            for (int r = 0; r < 16; ++r) { p0[r] = 0.f; p1[r] = 0.f; }
            const unsigned short* Ab = As[(2 * p) & 3];
            __builtin_amdgcn_s_setprio(1);
            #pragma unroll
            for (int kk = 0; kk < 8; ++kk) {
                bf16x8 Afr = *(const bf16x8*)&Ab[c * 128 + ((kk * 16 + h * 8) ^ ((c & 15) << 3))];
                p0 = __builtin_amdgcn_mfma_f32_32x32x16_bf16(Afr, Bf[0][kk], p0, 0, 0, 0);
                p1 = __builtin_amdgcn_mfma_f32_32x32x16_bf16(Afr, Bf[1][kk], p1, 0, 0, 0);
            }
            __builtin_amdgcn_s_setprio(0);
            #pragma unroll
            for (int r = 0; r < 16; ++r) {
                float a = p0[r], bb = p1[r];
                cw0 += a > 0.1f ? a : 0.f;
                cw1 += bb > 0.1f ? bb : 0.f;
            }
        }
        {
            f32x16 p0, p1;
            #pragma unroll
            for (int r = 0; r < 16; ++r) { p0[r] = 0.f; p1[r] = 0.f; }
            const unsigned short* Ab = As[(2 * p + 1) & 3];
            __builtin_amdgcn_s_setprio(1);
            #pragma unroll
            for (int kk = 0; kk < 8; ++kk) {
                bf16x8 Afr = *(const bf16x8*)&Ab[c * 128 + ((kk * 16 + h * 8) ^ ((c & 15) << 3))];
                p0 = __builtin_amdgcn_mfma_f32_32x32x16_bf16(Afr, Bf[0][kk], p0, 0, 0, 0);
                p1 = __builtin_amdgcn_mfma_f32_32x32x16_bf16(Afr, Bf[1][kk], p1, 0, 0, 0);
            }
            __builtin_amdgcn_s_setprio(0);
            if (p < 3) {
                unsigned short* An0 = As[(2 * p + 2) & 3];
                unsigned short* An1 = As[(2 * p + 3) & 3];
                *(u16x8*)&An0[soff] = w0; *(u16x8*)&An0[soff1] = w1;
                *(u16x8*)&An1[soff] = w2; *(u16x8*)&An1[soff1] = w3;
            }
            #pragma unroll
            for (int r = 0; r < 16; ++r) {
                float a = p0[r], bb = p1[r];
                cw0 += a > 0.1f ? a : 0.f;
                cw1 += bb > 0.1f ? bb : 0.f;
            }
        }
    }
    cw0 += __shfl_xor(cw0, 32);
    cw1 += __shfl_xor(cw1, 32);
    if (lane < 32) {
        atomicAdd(&cw[(size_t)b * M_PAD + mw + c], cw0);
        atomicAdd(&cw[(size_t)b * M_PAD + mw + 32 + c], cw1);
    }
}

// ---------------- gmat: fp16 MFMA full-G per block -> fp16 pG partials ----------------
__global__ __launch_bounds__(256) void k_gmatm(
    const _Float16* __restrict__ mnT, const float* __restrict__ cw,
    const float* __restrict__ norm_sq, float* __restrict__ ti,
    _Float16* __restrict__ pG) {
    __shared__ __align__(16) _Float16 effH[GM_CH];
    __shared__ float rb[4];
    const int tid = threadIdx.x, lane = tid & 63, wv = tid >> 6;
    const int c = lane & 31, h = lane >> 5;
    const int b = blockIdx.y;
    const int m0 = blockIdx.x * GM_CH;

    float tsum = 0.f;
    #pragma unroll
    for (int idx = tid; idx < GM_CH; idx += 256) {
        int m = m0 + idx;
        float e = 0.f;
        if (m < M_TOT) {
            float cc = cw[(size_t)b * M_PAD + m];
            float ns = norm_sq[m];
            e = (cc > 0.01f && ns > 1e-6f) ? cc : 0.f;
        }
        effH[idx] = (_Float16)e;
        tsum += e;
    }
    #pragma unroll
    for (int off = 1; off < 64; off <<= 1) tsum += __shfl_xor(tsum, off);
    if (lane == 0) rb[wv] = tsum;
    __syncthreads();
    if (tid == 0) atomicAdd(&ti[b], rb[0] + rb[1] + rb[2] + rb[3]);

    f32x16 a0, a1, a2, a3;
    #pragma unroll
    for (int r = 0; r < 16; ++r) { a0[r] = 0.f; a1[r] = 0.f; a2[r] = 0.f; a3[r] = 0.f; }

    const _Float16* Arow = mnT + (size_t)(wv * 32 + c) * M_PAD + m0;
    const _Float16* B0r = mnT + (size_t)(0 * 32 + c) * M_PAD + m0;
    const _Float16* B1r = mnT + (size_t)(1 * 32 + c) * M_PAD + m0;
    const _Float16* B2r = mnT + (size_t)(2 * 32 + c) * M_PAD + m0;
    const _Float16* B3r = mnT + (size_t)(3 * 32 + c) * M_PAD + m0;

    #pragma unroll 1
    for (int t = 0; t < GM_CH / 64; ++t) {
        #pragma unroll
        for (int kk = 0; kk < 4; ++kk) {
            const int mo = t * 64 + kk * 16 + h * 8;
            f16x8 au = *(const f16x8*)(Arow + mo);
            f16x8 ef = *(const f16x8*)&effH[mo];
            f16x8 af = au * ef;                      // v_pk_mul_f16 x4
            f16x8 B0 = *(const f16x8*)(B0r + mo);
            f16x8 B1 = *(const f16x8*)(B1r + mo);
            f16x8 B2 = *(const f16x8*)(B2r + mo);
            f16x8 B3 = *(const f16x8*)(B3r + mo);
            a0 = __builtin_amdgcn_mfma_f32_32x32x16_f16(af, B0, a0, 0, 0, 0);
            a1 = __builtin_amdgcn_mfma_f32_32x32x16_f16(af, B1, a1, 0, 0, 0);
            a2 = __builtin_amdgcn_mfma_f32_32x32x16_f16(af, B2, a2, 0, 0, 0);
            a3 = __builtin_amdgcn_mfma_f32_32x32x16_f16(af, B3, a3, 0, 0, 0);
        }
    }
    _Float16* o = pG + (size_t)(blockIdx.x * BB + b) * (DD * DD);
    #pragma unroll
    for (int r = 0; r < 16; ++r) {
        int rf = (r & 3) + 8 * (r >> 2) + 4 * h;
        o[(wv * 32 + rf) * DD + 0 * 32 + c] = (_Float16)a0[r];
        o[(wv * 32 + rf) * DD + 1 * 32 + c] = (_Float16)a1[r];
        o[(wv * 32 + rf) * DD + 2 * 32 + c] = (_Float16)a2[r];
        o[(wv * 32 + rf) * DD + 3 * 32 + c] = (_Float16)a3[r];
    }
}

// ---------------- gmat stage 2: reduce fp16 partials -> bf16 G ----------------
__global__ __launch_bounds__(256) void k_gmat2(const _Float16* __restrict__ pG,
                                               unsigned short* __restrict__ Gb) {
    __shared__ float red[4][64][8];
    const int tid = threadIdx.x;
    const int b = blockIdx.y;
    const int sl = tid & 63, cg = tid >> 6;
    const int f8i = blockIdx.x * 64 + sl;
    float acc[8] = {0.f, 0.f, 0.f, 0.f, 0.f, 0.f, 0.f, 0.f};
    for (int c = cg; c < GM_NCH; c += 4) {
        f16x8 p = *(const f16x8*)(pG + (size_t)(c * BB + b) * (DD * DD) + (size_t)f8i * 8);
        #pragma unroll
        for (int j = 0; j < 8; ++j) acc[j] += (float)p[j];
    }
    #pragma unroll
    for (int j = 0; j < 8; ++j) red[cg][sl][j] = acc[j];
    __syncthreads();
    if (tid < 64) {
        u16x8 o;
        #pragma unroll
        for (int j = 0; j < 8; ++j)
            o[j] = f2bf(red[0][tid][j] + red[1][tid][j] + red[2][tid][j] + red[3][tid][j]);
        *(u16x8*)&Gb[(size_t)b * DD * DD + (size_t)(blockIdx.x * 64 + tid) * 8] = o;
    }
}

// ---------------- final = raw + scale * (raw @ G_b), col-split: 256 blocks ----------------
__global__ __launch_bounds__(128) void k_final(
    const float* __restrict__ raw, const unsigned short* __restrict__ Gb,
    const float* __restrict__ ti, float* __restrict__ out) {
    const int tid = threadIdx.x, lane = tid & 63, wv = tid >> 6;   // wv 0..1
    const int col = lane & 31, hi = lane >> 5;
    const int t0 = blockIdx.x * 32;
    const int b = blockIdx.x >> 5;
    const int ct = blockIdx.y * 2 + wv;   // col tile 0..3

    bf16x8 Af[8];
    const float* rrow = raw + (size_t)(t0 + col) * DD + hi * 8;
    #pragma unroll
    for (int kk = 0; kk < 8; ++kk) {
        float4 p = *(const float4*)(rrow + kk * 16);
        float4 q = *(const float4*)(rrow + kk * 16 + 4);
        BF8 t;
        t.u[0] = f2bf(p.x); t.u[1] = f2bf(p.y); t.u[2] = f2bf(p.z); t.u[3] = f2bf(p.w);
        t.u[4] = f2bf(q.x); t.u[5] = f2bf(q.y); t.u[6] = f2bf(q.z); t.u[7] = f2bf(q.w);
        Af[kk] = t.b;
    }
    f32x16 acc;
    #pragma unroll
    for (int r = 0; r < 16; ++r) acc[r] = 0.f;
    const unsigned short* grow = Gb + (size_t)b * DD * DD + (size_t)(ct * 32 + col) * DD + hi * 8;
    #pragma unroll
    for (int kk = 0; kk < 8; ++kk) {
        bf16x8 Bw = *(const bf16x8*)(grow + kk * 16);
        acc = __builtin_amdgcn_mfma_f32_32x32x16_bf16(Af[kk], Bw, acc, 0, 0, 0);
    }
    float tib = ti[b];
    float scale = (tib > 0.01f) ? 0.5f / (tib + 1e-5f) : 0.0f;
    #pragma unroll
    for (int r = 0; r < 16; ++r) {
        int row = (r & 3) + 8 * (r >> 2) + 4 * hi;
        size_t idx = (size_t)(t0 + row) * DD + ct * 32 + col;
        out[idx] = raw[idx] + scale * acc[r];
    }
}

extern "C" void kernel_launch(void* const* d_in, const int* in_sizes, int n_in,
                              void* d_out, int out_size, void* d_ws, size_t ws_size,
                              hipStream_t stream) {
    const float* x   = (const float*)d_in[0];
    const float* mem = (const float*)d_in[1];
    const float* W1  = (const float*)d_in[2];
    const float* b1  = (const float*)d_in[3];
    const float* lg  = (const float*)d_in[4];
    const float* lb  = (const float*)d_in[5];
    const float* W2  = (const float*)d_in[6];
    const float* b2  = (const float*)d_in[7];
    float* out = (float*)d_out;

    float* wsf = (float*)d_ws;
    size_t off = 0;
    unsigned short* mnb = (unsigned short*)(wsf + off); off += (size_t)M_PAD * 64;
    _Float16* mnT = (_Float16*)(wsf + off);             off += (size_t)M_PAD * 64;
    float* norm_sq = wsf + off;                         off += M_PAD;
    unsigned short* xnb = (unsigned short*)(wsf + off); off += (size_t)BB * SS * 64;
    float* raw = wsf + off;                             off += (size_t)BB * SS * DD;
    float* cw  = wsf + off;                             off += (size_t)BB * M_PAD;
    unsigned short* Gb = (unsigned short*)(wsf + off);  off += (size_t)BB * DD * DD / 2;
    float* ti  = wsf + off;                             off += BB;
    _Float16* pG = (_Float16*)(wsf + off);              off += (size_t)GM_NCH * BB * DD * DD / 2;

    k_front<<<dim3(FMLP_BLOCKS + PREP_BLOCKS), 256, 0, stream>>>(
        x, W1, b1, lg, lb, W2, b2, mem, xnb, raw, mnb, mnT, norm_sq, ti, cw);
    k_cw<<<dim3(M_PAD / 256, 4, BB), 256, 0, stream>>>(xnb, mnb, cw);
    k_gmatm<<<dim3(GM_NCH, BB), 256, 0, stream>>>(mnT, cw, norm_sq, ti, pG);
    k_gmat2<<<dim3(DD * DD / 512, BB), 256, 0, stream>>>(pG, Gb);
    k_final<<<dim3(SS * BB / 32, 2), 128, 0, stream>>>(raw, Gb, ti, out);
}